// Round 2
// baseline (451.560 us; speedup 1.0000x reference)
//
#include <hip/hip_runtime.h>

#define NIMG 64
#define H 512
#define W 512

constexpr float THR_64  = 50.0f / 255.0f;          // level_idx=1: 64x64 details
constexpr float THR_128 = 50.0f / 2.0f / 255.0f;   // level_idx=2: 128x128
constexpr float THR_256 = 50.0f / 4.0f / 255.0f;   // level_idx=3: 256x256

__device__ __forceinline__ float wave_sum(float v) {
#pragma unroll
    for (int o = 32; o > 0; o >>= 1) v += __shfl_down(v, o, 64);
    return v;
}

__device__ __forceinline__ float clip01(float x) {
    return fminf(fmaxf(x, 0.0f), 1.0f);
}

__device__ __forceinline__ float4 clip4(float4 p) {
    p.x = clip01(p.x); p.y = clip01(p.y); p.z = clip01(p.z); p.w = clip01(p.w);
    return p;
}

// Kernel A: clip + n2v + tv + level-1 Haar DWT, no LDS main path.
// Wave = one row pair (rows 2*pr, 2*pr+1); lane i owns cols [8i, 8i+8).
// Block = 256 threads = 4 waves = 4 row pairs. Grid = 64 imgs * 64 = 4096.
__global__ __launch_bounds__(256) void kA(const float* __restrict__ pred,
                                          const float* __restrict__ noisy,
                                          const int* __restrict__ mask,
                                          float* __restrict__ acc,
                                          float* __restrict__ ll1) {
    __shared__ float red[4][4];

    const int tid = threadIdx.x;
    const int lane = tid & 63;
    const int wv = tid >> 6;
    const int bid = blockIdx.x;
    const int n = bid >> 6;
    const int pr = ((bid & 63) << 2) + wv;   // row pair 0..255
    const int r0 = pr << 1;
    const size_t base = (size_t)n * (H * W) + (size_t)r0 * W + (size_t)lane * 8;

    // --- independent global loads, all issued up front ---
    float4 p0a = *reinterpret_cast<const float4*>(pred + base);
    float4 p0b = *reinterpret_cast<const float4*>(pred + base + 4);
    float4 p1a = *reinterpret_cast<const float4*>(pred + base + W);
    float4 p1b = *reinterpret_cast<const float4*>(pred + base + W + 4);
    float4 nz0a = *reinterpret_cast<const float4*>(noisy + base);
    float4 nz0b = *reinterpret_cast<const float4*>(noisy + base + 4);
    float4 nz1a = *reinterpret_cast<const float4*>(noisy + base + W);
    float4 nz1b = *reinterpret_cast<const float4*>(noisy + base + W + 4);
    int4 mk0a = *reinterpret_cast<const int4*>(mask + base);
    int4 mk0b = *reinterpret_cast<const int4*>(mask + base + 4);
    int4 mk1a = *reinterpret_cast<const int4*>(mask + base + W);
    int4 mk1b = *reinterpret_cast<const int4*>(mask + base + W + 4);
    float4 ha = make_float4(0, 0, 0, 0), hb = make_float4(0, 0, 0, 0);
    const bool has_halo = (pr > 0);          // wave-uniform branch
    if (has_halo) {
        ha = clip4(*reinterpret_cast<const float4*>(pred + base - W));
        hb = clip4(*reinterpret_cast<const float4*>(pred + base - W + 4));
    }

    p0a = clip4(p0a); p0b = clip4(p0b); p1a = clip4(p1a); p1b = clip4(p1b);

    // --- n2v ---
    float n2v = 0.0f, msum = 0.0f;
    {
        float m;
        m = mk0a.x ? 1.f : 0.f; n2v += fabsf(p0a.x - nz0a.x) * m; msum += m;
        m = mk0a.y ? 1.f : 0.f; n2v += fabsf(p0a.y - nz0a.y) * m; msum += m;
        m = mk0a.z ? 1.f : 0.f; n2v += fabsf(p0a.z - nz0a.z) * m; msum += m;
        m = mk0a.w ? 1.f : 0.f; n2v += fabsf(p0a.w - nz0a.w) * m; msum += m;
        m = mk0b.x ? 1.f : 0.f; n2v += fabsf(p0b.x - nz0b.x) * m; msum += m;
        m = mk0b.y ? 1.f : 0.f; n2v += fabsf(p0b.y - nz0b.y) * m; msum += m;
        m = mk0b.z ? 1.f : 0.f; n2v += fabsf(p0b.z - nz0b.z) * m; msum += m;
        m = mk0b.w ? 1.f : 0.f; n2v += fabsf(p0b.w - nz0b.w) * m; msum += m;
        m = mk1a.x ? 1.f : 0.f; n2v += fabsf(p1a.x - nz1a.x) * m; msum += m;
        m = mk1a.y ? 1.f : 0.f; n2v += fabsf(p1a.y - nz1a.y) * m; msum += m;
        m = mk1a.z ? 1.f : 0.f; n2v += fabsf(p1a.z - nz1a.z) * m; msum += m;
        m = mk1a.w ? 1.f : 0.f; n2v += fabsf(p1a.w - nz1a.w) * m; msum += m;
        m = mk1b.x ? 1.f : 0.f; n2v += fabsf(p1b.x - nz1b.x) * m; msum += m;
        m = mk1b.y ? 1.f : 0.f; n2v += fabsf(p1b.y - nz1b.y) * m; msum += m;
        m = mk1b.z ? 1.f : 0.f; n2v += fabsf(p1b.z - nz1b.z) * m; msum += m;
        m = mk1b.w ? 1.f : 0.f; n2v += fabsf(p1b.w - nz1b.w) * m; msum += m;
    }

    // --- TV ---
    float tv = 0.0f;
    // horizontal, row r0 (7 interior diffs + boundary via shfl)
    tv += fabsf(p0a.y - p0a.x) + fabsf(p0a.z - p0a.y) + fabsf(p0a.w - p0a.z)
        + fabsf(p0b.x - p0a.w) + fabsf(p0b.y - p0b.x) + fabsf(p0b.z - p0b.y)
        + fabsf(p0b.w - p0b.z);
    // horizontal, row r1
    tv += fabsf(p1a.y - p1a.x) + fabsf(p1a.z - p1a.y) + fabsf(p1a.w - p1a.z)
        + fabsf(p1b.x - p1a.w) + fabsf(p1b.y - p1b.x) + fabsf(p1b.z - p1b.y)
        + fabsf(p1b.w - p1b.z);
    float nxt0 = __shfl_down(p0a.x, 1, 64);
    float nxt1 = __shfl_down(p1a.x, 1, 64);
    if (lane < 63) tv += fabsf(nxt0 - p0b.w) + fabsf(nxt1 - p1b.w);
    // vertical r0 vs r1 (always)
    tv += fabsf(p1a.x - p0a.x) + fabsf(p1a.y - p0a.y) + fabsf(p1a.z - p0a.z)
        + fabsf(p1a.w - p0a.w) + fabsf(p1b.x - p0b.x) + fabsf(p1b.y - p0b.y)
        + fabsf(p1b.z - p0b.z) + fabsf(p1b.w - p0b.w);
    // vertical halo (r0-1) vs r0
    if (has_halo) {
        tv += fabsf(p0a.x - ha.x) + fabsf(p0a.y - ha.y) + fabsf(p0a.z - ha.z)
            + fabsf(p0a.w - ha.w) + fabsf(p0b.x - hb.x) + fabsf(p0b.y - hb.y)
            + fabsf(p0b.z - hb.z) + fabsf(p0b.w - hb.w);
    }

    // --- level-1 Haar DWT: 4 quads per lane, write float4 LL ---
    float wav = 0.0f;
    float ll[4];
    {
        float a, b, c, d, ch, cv, cd;
        a = p0a.x; b = p0a.y; c = p1a.x; d = p1a.y;
        ll[0] = (a + b + c + d) * 0.5f;
        ch = (a + b - c - d) * 0.5f; cv = (a - b + c - d) * 0.5f; cd = (a - b - c + d) * 0.5f;
        wav += fminf(fabsf(ch), THR_256) + fminf(fabsf(cv), THR_256) + fminf(fabsf(cd), THR_256);
        a = p0a.z; b = p0a.w; c = p1a.z; d = p1a.w;
        ll[1] = (a + b + c + d) * 0.5f;
        ch = (a + b - c - d) * 0.5f; cv = (a - b + c - d) * 0.5f; cd = (a - b - c + d) * 0.5f;
        wav += fminf(fabsf(ch), THR_256) + fminf(fabsf(cv), THR_256) + fminf(fabsf(cd), THR_256);
        a = p0b.x; b = p0b.y; c = p1b.x; d = p1b.y;
        ll[2] = (a + b + c + d) * 0.5f;
        ch = (a + b - c - d) * 0.5f; cv = (a - b + c - d) * 0.5f; cd = (a - b - c + d) * 0.5f;
        wav += fminf(fabsf(ch), THR_256) + fminf(fabsf(cv), THR_256) + fminf(fabsf(cd), THR_256);
        a = p0b.z; b = p0b.w; c = p1b.z; d = p1b.w;
        ll[3] = (a + b + c + d) * 0.5f;
        ch = (a + b - c - d) * 0.5f; cv = (a - b + c - d) * 0.5f; cd = (a - b - c + d) * 0.5f;
        wav += fminf(fabsf(ch), THR_256) + fminf(fabsf(cv), THR_256) + fminf(fabsf(cd), THR_256);
    }
    *reinterpret_cast<float4*>(ll1 + (size_t)n * 65536 + (size_t)pr * 256 + (size_t)lane * 4) =
        make_float4(ll[0], ll[1], ll[2], ll[3]);

    // --- block reduction ---
    float v0 = wave_sum(n2v);
    float v1 = wave_sum(msum);
    float v2 = wave_sum(tv);
    float v3 = wave_sum(wav);
    if (lane == 0) { red[wv][0] = v0; red[wv][1] = v1; red[wv][2] = v2; red[wv][3] = v3; }
    __syncthreads();
    if (tid == 0) {
        atomicAdd(acc + 0, red[0][0] + red[1][0] + red[2][0] + red[3][0]);
        atomicAdd(acc + 1, red[0][1] + red[1][1] + red[2][1] + red[3][1]);
        atomicAdd(acc + 2, red[0][2] + red[1][2] + red[2][2] + red[3][2]);
        atomicAdd(acc + 3, red[0][3] + red[1][3] + red[2][3] + red[3][3]);
    }
}

// Kernel BC: fused level-2 + level-3. Block = 32x32 LL1 tile -> 16x16 LL2 in
// LDS -> 8x8 level-3 quads. Grid = 64 imgs * 64 tiles = 4096 blocks.
__global__ __launch_bounds__(256) void kBC(const float* __restrict__ ll1,
                                           float* __restrict__ acc) {
    __shared__ float tile[16][17];
    __shared__ float red2[4];
    __shared__ float red3[1];

    const int tid = threadIdx.x;
    const int bid = blockIdx.x;
    const int n = bid >> 6;
    const int t = bid & 63;
    const int R = (t >> 3) << 5;       // tile row origin in LL1
    const int C = (t & 7) << 5;        // tile col origin
    const int qr = tid >> 4;           // 0..15
    const int qc = tid & 15;           // 0..15

    const float* src = ll1 + (size_t)n * 65536 + (size_t)(R + 2 * qr) * 256 + C + 2 * qc;
    float2 top = *reinterpret_cast<const float2*>(src);
    float2 bot = *reinterpret_cast<const float2*>(src + 256);
    float a = top.x, b = top.y, c = bot.x, d = bot.y;
    float ll2v = (a + b + c + d) * 0.5f;
    float ch = (a + b - c - d) * 0.5f;
    float cv = (a - b + c - d) * 0.5f;
    float cd = (a - b - c + d) * 0.5f;
    float wav2 = fminf(fabsf(ch), THR_128) + fminf(fabsf(cv), THR_128) + fminf(fabsf(cd), THR_128);
    tile[qr][qc] = ll2v;

    float v2 = wave_sum(wav2);
    const int lane = tid & 63, wv = tid >> 6;
    if (lane == 0) red2[wv] = v2;
    __syncthreads();

    // level 3: 64 quads, wave 0 only
    if (tid < 64) {
        int qr3 = tid >> 3, qc3 = tid & 7;
        a = tile[2 * qr3][2 * qc3];     b = tile[2 * qr3][2 * qc3 + 1];
        c = tile[2 * qr3 + 1][2 * qc3]; d = tile[2 * qr3 + 1][2 * qc3 + 1];
        ch = (a + b - c - d) * 0.5f;
        cv = (a - b + c - d) * 0.5f;
        cd = (a - b - c + d) * 0.5f;
        float wav3 = fminf(fabsf(ch), THR_64) + fminf(fabsf(cv), THR_64) + fminf(fabsf(cd), THR_64);
        wav3 = wave_sum(wav3);
        if (tid == 0) red3[0] = wav3;
    }
    __syncthreads();
    if (tid == 0) {
        atomicAdd(acc + 4, red2[0] + red2[1] + red2[2] + red2[3]);
        atomicAdd(acc + 5, red3[0]);
    }
}

// Kernel D: compose final scalar
__global__ void kD(const float* __restrict__ acc, float* __restrict__ out) {
    float n2v = acc[0] / fmaxf(acc[1], 1.0f);
    float tv = acc[2] / 16744448.0f;                       // 64*511*512 (both terms)
    float wav = acc[3] * (1.0f / 37748736.0f)              // (1/3) / (3*64*256*256)
              + acc[4] * (1.0f / 6291456.0f)               // (1/2) / (3*64*128*128)
              + acc[5] * (1.0f / 786432.0f);               // 1     / (3*64*64*64)
    out[0] = 1.0f * n2v + 0.2f * wav + 0.01f * tv;
}

extern "C" void kernel_launch(void* const* d_in, const int* in_sizes, int n_in,
                              void* d_out, int out_size, void* d_ws, size_t ws_size,
                              hipStream_t stream) {
    (void)in_sizes; (void)n_in; (void)out_size; (void)ws_size;
    const float* pred  = (const float*)d_in[0];
    const float* noisy = (const float*)d_in[1];
    const int*   mask  = (const int*)d_in[2];

    float* acc = (float*)d_ws;                   // 6 accumulators
    float* ll1 = (float*)d_ws + 64;              // 64*256*256 floats = 16 MB

    hipMemsetAsync(d_ws, 0, 64 * sizeof(float), stream);
    kA<<<NIMG * 64, 256, 0, stream>>>(pred, noisy, mask, acc, ll1);
    kBC<<<NIMG * 64, 256, 0, stream>>>(ll1, acc);
    kD<<<1, 1, 0, stream>>>(acc, (float*)d_out);
}